// Round 1
// baseline (258.649 us; speedup 1.0000x reference)
//
#include <hip/hip_runtime.h>
#include <stdint.h>

typedef unsigned short u16;
typedef __attribute__((ext_vector_type(4))) float f32x4;
typedef __attribute__((ext_vector_type(8))) short s16x8;
typedef __attribute__((ext_vector_type(4))) unsigned short u16x4;
typedef __attribute__((ext_vector_type(8))) unsigned short u16x8;
typedef __attribute__((ext_vector_type(2))) unsigned int u32x2;

__device__ __forceinline__ u16 f2bf(float f) {
  union { float f; uint32_t u; } v; v.f = f;
  uint32_t r = (v.u + 0x7FFFu + ((v.u >> 16) & 1u)) >> 16;
  return (u16)r;
}

__device__ __forceinline__ void gload_lds16(const void* g, void* l) {
  __builtin_amdgcn_global_load_lds((const __attribute__((address_space(1))) uint32_t*)g,
                                   (__attribute__((address_space(3))) uint32_t*)l, 16, 0, 0);
}

// ---------------------------------------------------------------------------
// f32 -> bf16 weight conversion
// ---------------------------------------------------------------------------
__global__ __launch_bounds__(256) void cvt_kernel(const float* __restrict__ src,
                                                  u16* __restrict__ dst, int n) {
  const int i = (blockIdx.x * 256 + threadIdx.x) * 4;
  if (i < n) {
    f32x4 v = *(const f32x4*)(src + i);
    u16x4 p;
    p[0] = f2bf(v[0]); p[1] = f2bf(v[1]); p[2] = f2bf(v[2]); p[3] = f2bf(v[3]);
    *(u16x4*)(dst + i) = p;
  }
}

// ---------------------------------------------------------------------------
// Fused LayerNorm + transpose: x (B,C,N) f32 -> xn (B*N, C) bf16
// Block: 16 tokens, 256 threads. LDS tile [16][516] f32 (stride mult of 4 for
// aligned b128, 516%32==4 spreads banks).
// ---------------------------------------------------------------------------
__global__ __launch_bounds__(256) void ln_kernel(const float* __restrict__ x,
                                                 const float* __restrict__ lng,
                                                 const float* __restrict__ lnb,
                                                 u16* __restrict__ xn) {
  __shared__ float xt[16][516];
  __shared__ float ps[16][16], pq[16][16];
  __shared__ float smu[16], srs[16];
  const int tid = threadIdx.x;
  const int tok0 = blockIdx.x << 4;
  const int b = tok0 >> 10;
  const int nb = tok0 & 1023;
  const float* xb = x + (size_t)b * 512 * 1024 + nb;
  {
    const int n4 = (tid & 3) * 4;
    const int cr = tid >> 2;
#pragma unroll
    for (int it = 0; it < 8; ++it) {
      const int c = it * 64 + cr;
      f32x4 v = *(const f32x4*)(xb + (size_t)c * 1024 + n4);
      xt[n4 + 0][c] = v[0]; xt[n4 + 1][c] = v[1];
      xt[n4 + 2][c] = v[2]; xt[n4 + 3][c] = v[3];
    }
  }
  __syncthreads();
  {
    const int n = tid & 15, part = tid >> 4;
    float s = 0.f, q = 0.f;
#pragma unroll
    for (int i = 0; i < 8; ++i) {
      f32x4 v = *(const f32x4*)&xt[n][part * 32 + i * 4];
#pragma unroll
      for (int j = 0; j < 4; ++j) { s += v[j]; q += v[j] * v[j]; }
    }
    ps[part][n] = s; pq[part][n] = q;
  }
  __syncthreads();
  if (tid < 16) {
    float s = 0.f, q = 0.f;
#pragma unroll
    for (int p = 0; p < 16; ++p) { s += ps[p][tid]; q += pq[p][tid]; }
    const float mu = s * (1.f / 512.f);
    const float var = q * (1.f / 512.f) - mu * mu;
    smu[tid] = mu; srs[tid] = rsqrtf(var + 1e-5f);
  }
  __syncthreads();
  {
    const int n = tid >> 4, sub = tid & 15;
    const float mu = smu[n], rs = srs[n];
    u16* dst = xn + (size_t)(tok0 + n) * 512;
#pragma unroll
    for (int i = 0; i < 4; ++i) {
      const int c = (sub + 16 * i) * 8;
      f32x4 v0 = *(const f32x4*)&xt[n][c];
      f32x4 v1 = *(const f32x4*)&xt[n][c + 4];
      f32x4 g0 = *(const f32x4*)(lng + c);
      f32x4 g1 = *(const f32x4*)(lng + c + 4);
      f32x4 b0 = *(const f32x4*)(lnb + c);
      f32x4 b1 = *(const f32x4*)(lnb + c + 4);
      u16x8 pk;
#pragma unroll
      for (int j = 0; j < 4; ++j) {
        pk[j]     = f2bf((v0[j] - mu) * rs * g0[j] + b0[j]);
        pk[4 + j] = f2bf((v1[j] - mu) * rs * g1[j] + b1[j]);
      }
      *(u16x8*)(dst + c) = pk;
    }
  }
}

// ---------------------------------------------------------------------------
// BT GEMM (m97 structure): C[m,n] = sum_k A[m,k]*Bw[n,k]
// 128x128 tile, BK=32, 4 waves (2x2), 4x4 16x16x32 bf16 MFMA frags per wave.
// EPI==0: store bf16. EPI==1: f32 store + bias[row] + resid[row*N+col].
// blockIdx.z batches B/C/resid via strides (elements).
// ---------------------------------------------------------------------------
template <int EPI>
__global__ __launch_bounds__(256) void gemm_bt(const u16* __restrict__ A,
                                               const u16* __restrict__ Bw,
                                               void* __restrict__ Cout,
                                               const float* __restrict__ bias,
                                               const float* __restrict__ resid,
                                               int M, int N, int K,
                                               long bsz, long csz, long rsz) {
  __shared__ u16 Al[128 * 32];
  __shared__ u16 Bl[128 * 32];
  const int tid = threadIdx.x;
  const int w = tid >> 6, lane = tid & 63;
  const int lg = lane >> 4, l15 = lane & 15;
  const int wr = w >> 1, wc = w & 1;
  const int m0 = blockIdx.x * 128, n0 = blockIdx.y * 128;
  const int z = blockIdx.z;
  const u16* Bz = Bw + (size_t)z * bsz;
  const float* Rz = (EPI == 1) ? resid + (size_t)z * rsz : nullptr;

  f32x4 acc[4][4];
#pragma unroll
  for (int i = 0; i < 4; ++i)
#pragma unroll
    for (int j = 0; j < 4; ++j) acc[i][j] = (f32x4){0.f, 0.f, 0.f, 0.f};

  const int sr = lane >> 2, sch = (lane & 3) * 8;
  for (int k0 = 0; k0 < K; k0 += 32) {
    __syncthreads();
#pragma unroll
    for (int i = 0; i < 2; ++i) {
      gload_lds16(A + (size_t)(m0 + w * 32 + i * 16 + sr) * K + k0 + sch,
                  &Al[(w * 32 + i * 16) * 32]);
      gload_lds16(Bz + (size_t)(n0 + w * 32 + i * 16 + sr) * K + k0 + sch,
                  &Bl[(w * 32 + i * 16) * 32]);
    }
    __syncthreads();
    s16x8 af[4], bfr[4];
#pragma unroll
    for (int mi = 0; mi < 4; ++mi)
      af[mi] = *(const s16x8*)&Al[(wr * 64 + mi * 16 + l15) * 32 + lg * 8];
#pragma unroll
    for (int ni = 0; ni < 4; ++ni)
      bfr[ni] = *(const s16x8*)&Bl[(wc * 64 + ni * 16 + l15) * 32 + lg * 8];
#pragma unroll
    for (int mi = 0; mi < 4; ++mi)
#pragma unroll
      for (int ni = 0; ni < 4; ++ni)
        acc[mi][ni] = __builtin_amdgcn_mfma_f32_16x16x32_bf16(af[mi], bfr[ni], acc[mi][ni], 0, 0, 0);
  }

  if (EPI == 0) {
    u16* C = (u16*)Cout;
#pragma unroll
    for (int mi = 0; mi < 4; ++mi)
#pragma unroll
      for (int ni = 0; ni < 4; ++ni) {
        const int col = n0 + wc * 64 + ni * 16 + l15;
#pragma unroll
        for (int r = 0; r < 4; ++r) {
          const int row = m0 + wr * 64 + mi * 16 + lg * 4 + r;
          C[(size_t)row * N + col] = f2bf(acc[mi][ni][r]);
        }
      }
  } else {
    float* C = (float*)Cout + (size_t)z * csz;
#pragma unroll
    for (int mi = 0; mi < 4; ++mi)
#pragma unroll
      for (int ni = 0; ni < 4; ++ni) {
        const int col = n0 + wc * 64 + ni * 16 + l15;
#pragma unroll
        for (int r = 0; r < 4; ++r) {
          const int row = m0 + wr * 64 + mi * 16 + lg * 4 + r;
          C[(size_t)row * N + col] = acc[mi][ni][r] + bias[row] + Rz[(size_t)row * N + col];
        }
      }
  }
}

// ---------------------------------------------------------------------------
// Flash attention. Grid: 1024 = 8 q-blocks x 128 (b,h). Block: 4 waves,
// each wave owns 32 q-rows. KVBLK=64. Swapped QK^T (S^T = K*Q^T) so the
// softmax'd P feeds PV as the A operand with a purely lane-local repack.
// K staged via global_load_lds with XOR-swizzled source (bank-conflict-free
// ds_read_b128); V staged transposed as k-pair words (b64 frag reads).
// O transposed once at the end through LDS -> 64B/lane coalesced bf16 stores.
// ---------------------------------------------------------------------------
__global__ __launch_bounds__(256) void attn_kernel(const u16* __restrict__ qkv,
                                                   u16* __restrict__ ao) {
  __shared__ union {
    struct { u16 K[64 * 64]; uint32_t Vt[64 * 34]; } s;
    struct { float O[4 * 32 * 68]; float ls[4 * 32]; } e;
  } sm;
  const int tid = threadIdx.x;
  const int w = tid >> 6, lane = tid & 63;
  const int lg = lane >> 4, l15 = lane & 15;
  const int qb = blockIdx.x & 7, bh = blockIdx.x >> 3;
  const int b = bh >> 3, h = bh & 7;
  const size_t base = (size_t)b * 1024 * 1536;
  const int qtok0 = qb * 128 + w * 32;

  s16x8 qf[2][2];  // [dstep][qg]
#pragma unroll
  for (int s = 0; s < 2; ++s)
#pragma unroll
    for (int qg = 0; qg < 2; ++qg)
      qf[s][qg] = *(const s16x8*)(qkv + base + (size_t)(qtok0 + qg * 16 + l15) * 1536 +
                                  h * 64 + lg * 8 + 32 * s);

  f32x4 o[2][4];  // [qg][dblk]
#pragma unroll
  for (int qg = 0; qg < 2; ++qg)
#pragma unroll
    for (int db = 0; db < 4; ++db) o[qg][db] = (f32x4){0.f, 0.f, 0.f, 0.f};
  float mrun[2] = {-1e30f, -1e30f};
  float lrun[2] = {0.f, 0.f};
  const float CE = 0.125f * 1.44269504f;  // scale * log2(e)

  for (int k0 = 0; k0 < 1024; k0 += 64) {
    __syncthreads();
    {  // stage K, source-swizzled so LDS reads are conflict-neutral
      const int r = lane >> 3, ch = lane & 7;
#pragma unroll
      for (int i = 0; i < 2; ++i) {
        const int row = w * 16 + i * 8 + r;
        const u16* src = qkv + base + (size_t)(k0 + row) * 1536 + 512 + h * 64 +
                         ((ch ^ (row & 7)) * 8);
        gload_lds16(src, &sm.s.K[(w * 16 + i * 8) * 64]);
      }
    }
    {  // stage V transposed: Vt[d][kpair] words, u16 halves = k even/odd
      const int kk = tid & 63, dc = tid >> 6;
      const u16* v0p = qkv + base + (size_t)(k0 + kk) * 1536 + 1024 + h * 64 + dc * 8;
      u16x8 va = *(const u16x8*)v0p;
      u16x8 vc = *(const u16x8*)(v0p + 32);
      u16* vt16 = (u16*)sm.s.Vt;
      const int kp2 = kk >> 1, klo = kk & 1;
#pragma unroll
      for (int i = 0; i < 8; ++i) {
        const int d0 = dc * 8 + i;
        vt16[(d0 * 34 + kp2) * 2 + klo] = va[i];
        vt16[((d0 + 32) * 34 + kp2) * 2 + klo] = vc[i];
      }
    }
    __syncthreads();

    // S^T = K * Q^T : rows = k (4 groups of 16), cols = q (2 groups of 16)
    f32x4 st[4][2];
#pragma unroll
    for (int kg = 0; kg < 4; ++kg)
#pragma unroll
      for (int qg = 0; qg < 2; ++qg) st[kg][qg] = (f32x4){0.f, 0.f, 0.f, 0.f};
#pragma unroll
    for (int s = 0; s < 2; ++s)
#pragma unroll
      for (int kg = 0; kg < 4; ++kg) {
        const int row = kg * 16 + l15;
        s16x8 kf = *(const s16x8*)&sm.s.K[row * 64 + ((lg * 8 + 32 * s) ^ ((row & 7) << 3))];
#pragma unroll
        for (int qg = 0; qg < 2; ++qg)
          st[kg][qg] = __builtin_amdgcn_mfma_f32_16x16x32_bf16(kf, qf[s][qg], st[kg][qg], 0, 0, 0);
      }

    // online softmax per q-column (lane-local 16 vals + 2 shfl_xor)
    float pvv[2][16];
#pragma unroll
    for (int qg = 0; qg < 2; ++qg) {
      float tmax = -1e30f;
#pragma unroll
      for (int kg = 0; kg < 4; ++kg)
#pragma unroll
        for (int r = 0; r < 4; ++r) tmax = fmaxf(tmax, st[kg][qg][r]);
      tmax = fmaxf(tmax, __shfl_xor(tmax, 16));
      tmax = fmaxf(tmax, __shfl_xor(tmax, 32));
      const float mnew = fmaxf(mrun[qg], tmax);
      const float corr = exp2f((mrun[qg] - mnew) * CE);
      mrun[qg] = mnew;
      float tsum = 0.f;
#pragma unroll
      for (int kg = 0; kg < 4; ++kg)
#pragma unroll
        for (int r = 0; r < 4; ++r) {
          const float p = exp2f((st[kg][qg][r] - mnew) * CE);
          pvv[qg][kg * 4 + r] = p;
          tsum += p;
        }
      tsum += __shfl_xor(tsum, 16);
      tsum += __shfl_xor(tsum, 32);
      lrun[qg] = lrun[qg] * corr + tsum;
#pragma unroll
      for (int db = 0; db < 4; ++db)
#pragma unroll
        for (int r = 0; r < 4; ++r) o[qg][db][r] *= corr;
    }

    // pack P frags (lane-local, bijection matches V frag k-slots)
    s16x8 pa[2][2];  // [qg][khalf]
#pragma unroll
    for (int qg = 0; qg < 2; ++qg)
#pragma unroll
      for (int kh = 0; kh < 2; ++kh) {
        s16x8 f;
#pragma unroll
        for (int j = 0; j < 4; ++j) {
          f[j]     = (short)f2bf(pvv[qg][(2 * kh) * 4 + j]);
          f[4 + j] = (short)f2bf(pvv[qg][(2 * kh + 1) * 4 + j]);
        }
        pa[qg][kh] = f;
      }

    // O += P * V
#pragma unroll
    for (int kh = 0; kh < 2; ++kh)
#pragma unroll
      for (int db = 0; db < 4; ++db) {
        const int d = db * 16 + l15;
        const uint32_t* vtp = sm.s.Vt + d * 34;
        u32x2 va = *(const u32x2*)(vtp + 16 * kh + 2 * lg);
        u32x2 vb = *(const u32x2*)(vtp + 16 * kh + 8 + 2 * lg);
        s16x8 vf;
        vf[0] = (short)(va[0] & 0xffff); vf[1] = (short)(va[0] >> 16);
        vf[2] = (short)(va[1] & 0xffff); vf[3] = (short)(va[1] >> 16);
        vf[4] = (short)(vb[0] & 0xffff); vf[5] = (short)(vb[0] >> 16);
        vf[6] = (short)(vb[1] & 0xffff); vf[7] = (short)(vb[1] >> 16);
#pragma unroll
        for (int qg = 0; qg < 2; ++qg)
          o[qg][db] = __builtin_amdgcn_mfma_f32_16x16x32_bf16(pa[qg][kh], vf, o[qg][db], 0, 0, 0);
      }
  }

  // epilogue: transpose O through LDS, scale by 1/l, coalesced bf16 store
  __syncthreads();
  float* Ow = sm.e.O + w * 32 * 68;
#pragma unroll
  for (int qg = 0; qg < 2; ++qg)
#pragma unroll
    for (int db = 0; db < 4; ++db)
#pragma unroll
      for (int r = 0; r < 4; ++r)
        Ow[(qg * 16 + lg * 4 + r) * 68 + db * 16 + l15] = o[qg][db][r];
  if (lane < 16) {
    sm.e.ls[w * 32 + lane] = lrun[0];
    sm.e.ls[w * 32 + 16 + lane] = lrun[1];
  }
  __syncthreads();
  {
    const int q = lane & 31, dh = lane >> 5;
    const float inv = 1.0f / sm.e.ls[w * 32 + q];
    u16* dst = ao + (size_t)(b * 1024 + qtok0 + q) * 512 + h * 64 + dh * 32;
#pragma unroll
    for (int i = 0; i < 4; ++i) {
      f32x4 v0 = *(const f32x4*)&Ow[q * 68 + dh * 32 + i * 8];
      f32x4 v1 = *(const f32x4*)&Ow[q * 68 + dh * 32 + i * 8 + 4];
      u16x8 pk;
#pragma unroll
      for (int j = 0; j < 4; ++j) { pk[j] = f2bf(v0[j] * inv); pk[4 + j] = f2bf(v1[j] * inv); }
      *(u16x8*)(dst + i * 8) = pk;
    }
  }
}

// ---------------------------------------------------------------------------
extern "C" void kernel_launch(void* const* d_in, const int* in_sizes, int n_in,
                              void* d_out, int out_size, void* d_ws, size_t ws_size,
                              hipStream_t stream) {
  const float* x      = (const float*)d_in[0];
  const float* qkv_w  = (const float*)d_in[1];
  const float* proj_w = (const float*)d_in[2];
  const float* proj_b = (const float*)d_in[3];
  const float* ln_g   = (const float*)d_in[4];
  const float* ln_b   = (const float*)d_in[5];
  float* out = (float*)d_out;

  char* ws = (char*)d_ws;
  u16* xn  = (u16*)ws;                                  // 16384x512  bf16 (16 MB)
  u16* qkv = (u16*)(ws + (size_t)16 * 1024 * 1024);     // 16384x1536 bf16 (48 MB)
  u16* ao  = (u16*)(ws + (size_t)64 * 1024 * 1024);     // 16384x512  bf16 (16 MB)
  u16* qw  = (u16*)(ws + (size_t)80 * 1024 * 1024);     // 1536x512 bf16
  u16* pw  = qw + 1536 * 512;                           // 512x512 bf16

  cvt_kernel<<<768, 256, 0, stream>>>(qkv_w, qw, 1536 * 512);
  cvt_kernel<<<256, 256, 0, stream>>>(proj_w, pw, 512 * 512);
  ln_kernel<<<1024, 256, 0, stream>>>(x, ln_g, ln_b, xn);
  // qkv = xn @ qkv_w^T  (M=16384 tokens, N=1536, K=512)
  gemm_bt<0><<<dim3(128, 12, 1), 256, 0, stream>>>(xn, qw, qkv, nullptr, nullptr,
                                                   16384, 1536, 512, 0, 0, 0);
  attn_kernel<<<1024, 256, 0, stream>>>(qkv, ao);
  // out[b,c,n] = sum_k proj_w[c,k]*ao[b,n,k] + proj_b[c] + x[b,c,n]
  gemm_bt<1><<<dim3(4, 8, 16), 256, 0, stream>>>(pw, ao, out, proj_b, x,
                                                 512, 1024, 512,
                                                 (long)1024 * 512, (long)512 * 1024,
                                                 (long)512 * 1024);
}